// Round 4
// baseline (89.335 us; speedup 1.0000x reference)
//
#include <hip/hip_runtime.h>
#include <math.h>

// Problem constants (from reference): B=4, S=4096, H=768, L=8, fp32.
constexpr int kB = 4, kS = 4096, kH = 768, kL = 8;
constexpr int kBS = kB * kS;                       // 16384 rows
constexpr size_t kLayerStride = (size_t)kBS * kH;  // floats between layers
constexpr int kNChunk = 32;
constexpr int kChunk = kH / kNChunk;               // 24
constexpr float kInvSqrtH = 0.03608439182435161f;  // 1/sqrt(768)

// Clang ext-vector (NOT HIP_vector_type) — required by __builtin_nontemporal_*.
typedef float f32x4 __attribute__((ext_vector_type(4)));

// Stage 1: partial qW[j] over an i-chunk. grid=(H/256, kNChunk), block=256.
// 96 blocks: spreads the 2.4 MB W_key read across 96 CUs (per-CU BW wall
// ~10 B/cyc makes few-block variants 10x slower — measured reasoning R3).
__global__ void qw_partial_kernel(const float* __restrict__ Wk,
                                  const float* __restrict__ q,
                                  float* __restrict__ part) {
    int j = blockIdx.x * 256 + threadIdx.x;  // 0..767, coalesced over j
    int i0 = blockIdx.y * kChunk;
    float s = 0.f;
#pragma unroll
    for (int k = 0; k < kChunk; ++k)
        s = fmaf(q[i0 + k], Wk[(size_t)(i0 + k) * kH + j], s);
    part[blockIdx.y * kH + j] = s;
}

// Stage 2: reduce partials, fold in 1/sqrt(H). grid=H/64=12 blocks, block=64.
__global__ void qw_reduce_kernel(const float* __restrict__ part,
                                 float* __restrict__ qw) {
    int j = blockIdx.x * 64 + threadIdx.x;
    float s = 0.f;
#pragma unroll
    for (int c = 0; c < kNChunk; ++c) s += part[c * kH + j];
    qw[j] = s * kInvSqrtH;
}

// Main fused kernel: one 64-lane wave per (b,s) row.
//   P0: qv loads first (L2-resident; complete under the row-load latency)
//   P1: all 24 NT f32x4 row loads in flight (24 KB/wave in VGPRs)
//   P2: dots (c-outer keeps peak VGPR < 128 cliff)
//   P3: butterfly reduce + lane-local softmax over L=8
//   P4: weighted sum, PLAIN f32x4 store (fills hit 7 TB/s with plain stores;
//       NT-store has no cache-protection upside here)
__global__ __launch_bounds__(256, 4) void attn_fused_kernel(
        const float* __restrict__ pre,
        const float* __restrict__ qw,
        float* __restrict__ out) {
    const int wid = threadIdx.x >> 6;
    const int lane = threadIdx.x & 63;
    const int bs = blockIdx.x * 4 + wid;

    const f32x4* __restrict__ row =
        reinterpret_cast<const f32x4*>(pre) + (size_t)bs * (kH / 4);
    const f32x4* __restrict__ qw4 = reinterpret_cast<const f32x4*>(qw);

    // P0 — query-projection fragments first.
    f32x4 qv[3];
#pragma unroll
    for (int c = 0; c < 3; ++c) qv[c] = qw4[c * 64 + lane];

    // P1 — all row loads in flight (24 KB/wave outstanding).
    f32x4 v[kL][3];
#pragma unroll
    for (int l = 0; l < kL; ++l) {
        const f32x4* p = row + (size_t)l * (kLayerStride / 4);
#pragma unroll
        for (int c = 0; c < 3; ++c)
            v[l][c] = __builtin_nontemporal_load(p + c * 64 + lane);
    }

    // P2 — per-lane partial dots.
    float d[kL];
#pragma unroll
    for (int l = 0; l < kL; ++l) d[l] = 0.f;
#pragma unroll
    for (int c = 0; c < 3; ++c) {
#pragma unroll
        for (int l = 0; l < kL; ++l) {
            d[l] = fmaf(v[l][c].x, qv[c].x, d[l]);
            d[l] = fmaf(v[l][c].y, qv[c].y, d[l]);
            d[l] = fmaf(v[l][c].z, qv[c].z, d[l]);
            d[l] = fmaf(v[l][c].w, qv[c].w, d[l]);
        }
    }

    // P3 — butterfly reduce: all 64 lanes end with full per-layer dots.
#pragma unroll
    for (int off = 32; off > 0; off >>= 1) {
#pragma unroll
        for (int l = 0; l < kL; ++l) d[l] += __shfl_xor(d[l], off, 64);
    }

    // Softmax over L=8 (lane-local, identical in all lanes).
    float m = d[0];
#pragma unroll
    for (int l = 1; l < kL; ++l) m = fmaxf(m, d[l]);
    float sum = 0.f;
#pragma unroll
    for (int l = 0; l < kL; ++l) { d[l] = __expf(d[l] - m); sum += d[l]; }
    const float inv = 1.f / sum;
#pragma unroll
    for (int l = 0; l < kL; ++l) d[l] *= inv;

    // P4 — weighted sum + coalesced plain store.
    f32x4* __restrict__ o4 =
        reinterpret_cast<f32x4*>(out) + (size_t)bs * (kH / 4);
#pragma unroll
    for (int c = 0; c < 3; ++c) {
        f32x4 o = {0.f, 0.f, 0.f, 0.f};
#pragma unroll
        for (int l = 0; l < kL; ++l) {
            o.x = fmaf(d[l], v[l][c].x, o.x);
            o.y = fmaf(d[l], v[l][c].y, o.y);
            o.z = fmaf(d[l], v[l][c].z, o.z);
            o.w = fmaf(d[l], v[l][c].w, o.w);
        }
        o4[c * 64 + lane] = o;
    }
}

extern "C" void kernel_launch(void* const* d_in, const int* in_sizes, int n_in,
                              void* d_out, int out_size, void* d_ws, size_t ws_size,
                              hipStream_t stream) {
    // setup_inputs order: 0=current_output (UNUSED by reference), 1=preceding,
    // 2=W_key, 3=query. All fp32.
    const float* pre = (const float*)d_in[1];
    const float* Wk  = (const float*)d_in[2];
    const float* q   = (const float*)d_in[3];
    float* out = (float*)d_out;

    // Workspace layout: qW [768 floats] | partials [32*768 floats] (~101 KB).
    float* qw   = (float*)d_ws;
    float* part = qw + kH;

    dim3 g1(kH / 256, kNChunk);
    qw_partial_kernel<<<g1, 256, 0, stream>>>(Wk, q, part);
    qw_reduce_kernel<<<kH / 64, 64, 0, stream>>>(part, qw);
    attn_fused_kernel<<<kBS / 4, 256, 0, stream>>>(pre, qw, out);
}

// Round 5
// 82.593 us; speedup vs baseline: 1.0816x; 1.0816x over previous
//
#include <hip/hip_runtime.h>
#include <math.h>

// Problem constants (from reference): B=4, S=4096, H=768, L=8, fp32.
constexpr int kB = 4, kS = 4096, kH = 768, kL = 8;
constexpr int kBS = kB * kS;                       // 16384 rows
constexpr size_t kLayerStride = (size_t)kBS * kH;  // floats between layers
constexpr float kInvSqrtH = 0.03608439182435161f;  // 1/sqrt(768)

// Clang ext-vector (NOT HIP_vector_type) — required by __builtin_nontemporal_*.
typedef float f32x4 __attribute__((ext_vector_type(4)));

// Fused qW kernel: qw[j] = (sum_i q[i]*W[i][j]) / sqrt(H), one dispatch.
// grid=96, block=256. Block b owns 8 j-columns; thread t: jj=t&7, ic=t>>3
// (32 i-chunks x 24). 96 blocks keeps the 2.4 MB W_key read spread across
// CUs (per-CU HBM wall ~10 B/cyc — R3 arithmetic). LDS reduce is
// conflict-free: writes are linear (addr=tid); read phase is stride-8 over
// 8 threads -> 8 distinct banks.
__global__ __launch_bounds__(256) void qw_fused_kernel(
        const float* __restrict__ Wk,
        const float* __restrict__ q,
        float* __restrict__ qw) {
    __shared__ float lds[32][8];
    const int tid = threadIdx.x;
    const int jj = tid & 7;
    const int ic = tid >> 3;            // 0..31
    const int j = blockIdx.x * 8 + jj;  // 0..767
    const int i0 = ic * 24;

    float s = 0.f;
#pragma unroll
    for (int k = 0; k < 24; ++k)
        s = fmaf(q[i0 + k], Wk[(size_t)(i0 + k) * kH + j], s);
    lds[ic][jj] = s;
    __syncthreads();

    if (tid < 8) {
        float acc = 0.f;
#pragma unroll
        for (int c = 0; c < 32; ++c) acc += lds[c][tid];
        qw[blockIdx.x * 8 + tid] = acc * kInvSqrtH;
    }
}

// Main fused kernel (R3-exact): one 64-lane wave per (b,s) row.
//   P1: all 24 NT f32x4 row loads in flight (24 KB/wave in VGPRs)
//   P2: dots — qv loaded INSIDE the c-loop so only one f32x4 of it is live
//       at a time (peak VGPR < 128 cliff; hoisting it regressed R4 by 5.5us)
//   P3: butterfly reduce + lane-local softmax over L=8
//   P4: weighted sum, NT f32x4 store (dropping NT-store was R4 suspect #2)
__global__ __launch_bounds__(256, 4) void attn_fused_kernel(
        const float* __restrict__ pre,
        const float* __restrict__ qw,
        float* __restrict__ out) {
    const int wid = threadIdx.x >> 6;
    const int lane = threadIdx.x & 63;
    const int bs = blockIdx.x * 4 + wid;

    const f32x4* __restrict__ row =
        reinterpret_cast<const f32x4*>(pre) + (size_t)bs * (kH / 4);
    const f32x4* __restrict__ qw4 = reinterpret_cast<const f32x4*>(qw);

    // P1 — all row loads in flight (24 KB/wave outstanding).
    f32x4 v[kL][3];
#pragma unroll
    for (int l = 0; l < kL; ++l) {
        const f32x4* p = row + (size_t)l * (kLayerStride / 4);
#pragma unroll
        for (int c = 0; c < 3; ++c)
            v[l][c] = __builtin_nontemporal_load(p + c * 64 + lane);
    }

    // P2 — per-lane partial dots.
    float d[kL];
#pragma unroll
    for (int l = 0; l < kL; ++l) d[l] = 0.f;
#pragma unroll
    for (int c = 0; c < 3; ++c) {
        const f32x4 qv = qw4[c * 64 + lane];  // L2-broadcast, one live at a time
#pragma unroll
        for (int l = 0; l < kL; ++l) {
            d[l] = fmaf(v[l][c].x, qv.x, d[l]);
            d[l] = fmaf(v[l][c].y, qv.y, d[l]);
            d[l] = fmaf(v[l][c].z, qv.z, d[l]);
            d[l] = fmaf(v[l][c].w, qv.w, d[l]);
        }
    }

    // P3 — butterfly reduce: all 64 lanes end with full per-layer dots.
#pragma unroll
    for (int off = 32; off > 0; off >>= 1) {
#pragma unroll
        for (int l = 0; l < kL; ++l) d[l] += __shfl_xor(d[l], off, 64);
    }

    // Softmax over L=8 (lane-local, identical in all lanes).
    float m = d[0];
#pragma unroll
    for (int l = 1; l < kL; ++l) m = fmaxf(m, d[l]);
    float sum = 0.f;
#pragma unroll
    for (int l = 0; l < kL; ++l) { d[l] = __expf(d[l] - m); sum += d[l]; }
    const float inv = 1.f / sum;
#pragma unroll
    for (int l = 0; l < kL; ++l) d[l] *= inv;

    // P4 — weighted sum + coalesced NT store.
    f32x4* __restrict__ o4 =
        reinterpret_cast<f32x4*>(out) + (size_t)bs * (kH / 4);
#pragma unroll
    for (int c = 0; c < 3; ++c) {
        f32x4 o = {0.f, 0.f, 0.f, 0.f};
#pragma unroll
        for (int l = 0; l < kL; ++l) {
            o.x = fmaf(d[l], v[l][c].x, o.x);
            o.y = fmaf(d[l], v[l][c].y, o.y);
            o.z = fmaf(d[l], v[l][c].z, o.z);
            o.w = fmaf(d[l], v[l][c].w, o.w);
        }
        __builtin_nontemporal_store(o, o4 + c * 64 + lane);
    }
}

extern "C" void kernel_launch(void* const* d_in, const int* in_sizes, int n_in,
                              void* d_out, int out_size, void* d_ws, size_t ws_size,
                              hipStream_t stream) {
    // setup_inputs order: 0=current_output (UNUSED by reference), 1=preceding,
    // 2=W_key, 3=query. All fp32.
    const float* pre = (const float*)d_in[1];
    const float* Wk  = (const float*)d_in[2];
    const float* q   = (const float*)d_in[3];
    float* out = (float*)d_out;

    // Workspace: qW [768 floats].
    float* qw = (float*)d_ws;

    qw_fused_kernel<<<kH / 8, 256, 0, stream>>>(Wk, q, qw);
    attn_fused_kernel<<<kBS / 4, 256, 0, stream>>>(pre, qw, out);
}